// Round 1
// 1275.137 us; speedup vs baseline: 1.6351x; 1.6351x over previous
//
#include <hip/hip_runtime.h>
#include <math.h>

#define NB 8
#define NT1 2048
#define NT2 512
#define NC 384
#define ND 192
#define NF 1536
#define NKI 3456   // 9*384 implicit-GEMM K for conv
#define TPAD 2056  // 2048 + 4 guard rows top and bottom

typedef __attribute__((ext_vector_type(8))) short bf16x8;
typedef __attribute__((ext_vector_type(4))) float f32x4;

#define GLOAD16(gsrc, ldst) \
  __builtin_amdgcn_global_load_lds((const __attribute__((address_space(1))) void*)(gsrc), \
                                   (__attribute__((address_space(3))) void*)(ldst), 16, 0, 0)

static __device__ __forceinline__ unsigned short f2bf(float f) {
  unsigned int u = __float_as_uint(f);
  unsigned int r = (u + 0x7fffu + ((u >> 16) & 1u)) >> 16;
  return (unsigned short)r;
}

static __device__ __forceinline__ float warp_sum(float v) {
#pragma unroll
  for (int off = 32; off > 0; off >>= 1) v += __shfl_xor(v, off);
  return v;
}

// x += alpha * sinusoidal positional embedding (fairseq style, pos = t+1)
__global__ __launch_bounds__(256) void k_add_pos(const float* __restrict__ x,
    const float* __restrict__ alpha_p, float* __restrict__ y, int T, int total) {
  int i = blockIdx.x * 256 + threadIdx.x;
  if (i >= total) return;
  int c = i % NC;
  int t = (i / NC) % T;
  int j = (c < 192) ? c : (c - 192);
  float freq = expf(-0.0482216773f * (float)j);   // ln(10000)/191
  float ang = (float)(t + 1) * freq;
  float sp = (c < 192) ? sinf(ang) : cosf(ang);
  y[i] = x[i] + alpha_p[0] * sp;
}

// LayerNorm over last dim (384). One wave per row. fp32 out.
__global__ __launch_bounds__(256) void k_ln(const float* __restrict__ x,
    const float* __restrict__ g, const float* __restrict__ b,
    float* __restrict__ y, int nrows) {
  int row = blockIdx.x * 4 + (threadIdx.x >> 6);
  int lane = threadIdx.x & 63;
  if (row >= nrows) return;
  const float* xr = x + (size_t)row * NC;
  float v[6];
  float s = 0.f, s2 = 0.f;
#pragma unroll
  for (int i = 0; i < 6; ++i) {
    float t = xr[lane + 64 * i];
    v[i] = t; s += t; s2 += t * t;
  }
  s = warp_sum(s); s2 = warp_sum(s2);
  float mean = s * (1.f / NC);
  float var = s2 * (1.f / NC) - mean * mean;
  float rs = rsqrtf(var + 1e-5f);
  float* yr = y + (size_t)row * NC;
#pragma unroll
  for (int i = 0; i < 6; ++i) {
    int cc = lane + 64 * i;
    yr[cc] = (v[i] - mean) * rs * g[cc] + b[cc];
  }
}

// LayerNorm -> bf16 into guard-padded [8][2056][384] buffer (row t -> t+4)
__global__ __launch_bounds__(256) void k_ln_bf16p(const float* __restrict__ x,
    const float* __restrict__ g, const float* __restrict__ b,
    unsigned short* __restrict__ ypad) {
  int row = blockIdx.x * 4 + (threadIdx.x >> 6);
  int lane = threadIdx.x & 63;
  const float* xr = x + (size_t)row * NC;
  float v[6];
  float s = 0.f, s2 = 0.f;
#pragma unroll
  for (int i = 0; i < 6; ++i) {
    float t = xr[lane + 64 * i];
    v[i] = t; s += t; s2 += t * t;
  }
  s = warp_sum(s); s2 = warp_sum(s2);
  float mean = s * (1.f / NC);
  float var = s2 * (1.f / NC) - mean * mean;
  float rs = rsqrtf(var + 1e-5f);
  int bb = row >> 11, t = row & 2047;
  unsigned short* yr = ypad + ((size_t)(bb * TPAD + t + 4)) * NC;
#pragma unroll
  for (int i = 0; i < 6; ++i) {
    int cc = lane + 64 * i;
    yr[cc] = f2bf((v[i] - mean) * rs * g[cc] + b[cc]);
  }
}

// zero the 4 guard rows top+bottom of each batch slab in ypad
__global__ __launch_bounds__(256) void k_zero_guard(unsigned short* __restrict__ ypad) {
  int i = blockIdx.x * 256 + threadIdx.x;   // 8*8*384 = 24576
  if (i >= 24576) return;
  int c = i % NC;
  int r = (i / NC) % 8;
  int b = i / (NC * 8);
  int t = (r < 4) ? r : (2048 + r);         // rows 0..3 and 2052..2055
  ypad[((size_t)b * TPAD + t) * NC + c] = 0;
}

// C[M,N] = alpha * A[M,K] @ W[N,K]^T (+bias[n]) (+res[m,n]); 64x64 tile, fp32.
// If Cb != null, write bf16 to Cb instead of fp32 to C.
__global__ __launch_bounds__(256) void k_gemm(const float* __restrict__ A,
    const float* __restrict__ W, float* __restrict__ C, unsigned short* __restrict__ Cb,
    const float* __restrict__ bias, const float* __restrict__ res,
    int M, int N, int K, float alpha) {
  __shared__ float As[64][17];
  __shared__ float Ws[64][17];
  const int bm = blockIdx.y * 64, bn = blockIdx.x * 64;
  const int tid = threadIdx.x;
  const int tx = tid & 15, ty = tid >> 4;
  const int lr = tid >> 2, lq = (tid & 3) << 2;
  float acc[4][4] = {};
  const float* Ap = A + (size_t)(bm + lr) * K + lq;
  const float* Wp = W + (size_t)(bn + lr) * K + lq;
  for (int kt = 0; kt < K; kt += 16) {
    float4 av = *(const float4*)(Ap + kt);
    float4 wv = *(const float4*)(Wp + kt);
    As[lr][lq + 0] = av.x; As[lr][lq + 1] = av.y; As[lr][lq + 2] = av.z; As[lr][lq + 3] = av.w;
    Ws[lr][lq + 0] = wv.x; Ws[lr][lq + 1] = wv.y; Ws[lr][lq + 2] = wv.z; Ws[lr][lq + 3] = wv.w;
    __syncthreads();
#pragma unroll
    for (int k2 = 0; k2 < 16; ++k2) {
      float a0 = As[ty * 4 + 0][k2], a1 = As[ty * 4 + 1][k2];
      float a2 = As[ty * 4 + 2][k2], a3 = As[ty * 4 + 3][k2];
      float w0 = Ws[tx * 4 + 0][k2], w1 = Ws[tx * 4 + 1][k2];
      float w2 = Ws[tx * 4 + 2][k2], w3 = Ws[tx * 4 + 3][k2];
      acc[0][0] += a0 * w0; acc[0][1] += a0 * w1; acc[0][2] += a0 * w2; acc[0][3] += a0 * w3;
      acc[1][0] += a1 * w0; acc[1][1] += a1 * w1; acc[1][2] += a1 * w2; acc[1][3] += a1 * w3;
      acc[2][0] += a2 * w0; acc[2][1] += a2 * w1; acc[2][2] += a2 * w2; acc[2][3] += a2 * w3;
      acc[3][0] += a3 * w0; acc[3][1] += a3 * w1; acc[3][2] += a3 * w2; acc[3][3] += a3 * w3;
    }
    __syncthreads();
  }
#pragma unroll
  for (int i = 0; i < 4; ++i) {
    int m = bm + ty * 4 + i;
#pragma unroll
    for (int j = 0; j < 4; ++j) {
      int n = bn + tx * 4 + j;
      float val = acc[i][j] * alpha;
      if (bias) val += bias[n];
      if (res) val += res[(size_t)m * N + n];
      if (Cb) Cb[(size_t)m * N + n] = f2bf(val);
      else C[(size_t)m * N + n] = val;
    }
  }
}

// pack + convert cw[f][c][kk] -> cwp[f][kk*384+c] bf16 (k-major rows of len 3456)
__global__ __launch_bounds__(256) void k_pack_cw_bf16(const float* __restrict__ cw,
    unsigned short* __restrict__ cwp) {
  int i = blockIdx.x * 256 + threadIdx.x;
  if (i >= NF * NKI) return;
  int cc = i % NC;
  int kk = (i / NC) % 9;
  int f = i / NKI;
  cwp[i] = f2bf(cw[(size_t)f * NKI + cc * 9 + kk]);
}

__global__ __launch_bounds__(256) void k_cvt_bf16(const float* __restrict__ x,
    unsigned short* __restrict__ y, int n) {
  int i = blockIdx.x * 256 + threadIdx.x;
  if (i < n) y[i] = f2bf(x[i]);
}

// V transpose: vbb [b*512+j][h*192+d] bf16 -> vtb [(b*2+h)*192+d][512 j] bf16
__global__ __launch_bounds__(256) void k_vt(const unsigned short* __restrict__ vbb,
    unsigned short* __restrict__ vtb) {
  int i = blockIdx.x * 256 + threadIdx.x;   // 8*2*192*512 = 1572864
  if (i >= 1572864) return;
  int j = i & 511;
  int i2 = i >> 9;
  int d = i2 % 192;
  int bh = i2 / 192;
  int b = bh >> 1, h = bh & 1;
  vtb[i] = vbb[(size_t)(b * 512 + j) * NC + h * ND + d];
}

// Conv1d(C->4C,k=9,SAME) implicit GEMM, bf16 MFMA 128x128xBK32 (m97 structure),
// fused (+cb)*9^-0.5 -> gelu(exact) -> bf16 store.
__global__ __launch_bounds__(256) void k_conv_mfma(
    const unsigned short* __restrict__ Ypad,
    const unsigned short* __restrict__ Wp,
    const float* __restrict__ cb,
    unsigned short* __restrict__ H) {
  __shared__ unsigned short As[128 * 32];
  __shared__ unsigned short Bs[128 * 32];
  const int bn = blockIdx.x * 128;
  const int bm = blockIdx.y * 128;
  const int b = bm >> 11, t0 = bm & 2047;
  const int tid = threadIdx.x;
  const int lane = tid & 63, wv = tid >> 6;
  const int wr = (wv >> 1) * 64, wc = (wv & 1) * 64;
  f32x4 acc[4][4] = {};

  const int chunk = wv * 2;
  const int rloc = chunk * 16 + (lane >> 2);
  const int slot = (lane & 3) * 8;
  const size_t abase = ((size_t)(b * TPAD + t0 + rloc)) * NC + slot;
  const size_t bbase = ((size_t)(bn + rloc)) * NKI + slot;
  unsigned short* AsW0 = &As[chunk * 512];
  unsigned short* AsW1 = &As[(chunk + 1) * 512];
  unsigned short* BsW0 = &Bs[chunk * 512];
  unsigned short* BsW1 = &Bs[(chunk + 1) * 512];

  const int rsel = lane & 15, ksel = (lane >> 4) * 8;

  for (int kt = 0; kt < NKI; kt += 32) {
    const int kk = kt / NC;
    const int c0 = kt - kk * NC;
    const size_t aoff = (size_t)kk * NC + c0;
    GLOAD16(Ypad + abase + aoff, AsW0);
    GLOAD16(Ypad + abase + aoff + (size_t)16 * NC, AsW1);
    GLOAD16(Wp + bbase + kt, BsW0);
    GLOAD16(Wp + bbase + kt + (size_t)16 * NKI, BsW1);
    __syncthreads();
    bf16x8 af[4], bfr[4];
#pragma unroll
    for (int m = 0; m < 4; ++m)
      af[m] = *(const bf16x8*)&As[(wr + m * 16 + rsel) * 32 + ksel];
#pragma unroll
    for (int n = 0; n < 4; ++n)
      bfr[n] = *(const bf16x8*)&Bs[(wc + n * 16 + rsel) * 32 + ksel];
#pragma unroll
    for (int m = 0; m < 4; ++m)
#pragma unroll
      for (int n = 0; n < 4; ++n)
        acc[m][n] = __builtin_amdgcn_mfma_f32_16x16x32_bf16(af[m], bfr[n], acc[m][n], 0, 0, 0);
    __syncthreads();
  }

  const int col0 = bn + wc + (lane & 15);
  const int row0 = bm + wr + (lane >> 4) * 4;
#pragma unroll
  for (int m = 0; m < 4; ++m) {
#pragma unroll
    for (int n = 0; n < 4; ++n) {
      int col = col0 + n * 16;
      float cbv = cb[col];
#pragma unroll
      for (int r = 0; r < 4; ++r) {
        int row = row0 + m * 16 + r;
        float xv = (acc[m][n][r] + cbv) * 0.33333333333333333f;
        float ge = 0.5f * xv * (1.f + erff(xv * 0.70710678118654752f));
        H[(size_t)row * NF + col] = f2bf(ge);
      }
    }
  }
}

// FFN linear: x1a[m][n] += H[m][:]@lw[n][:] + lb[n].  bf16 MFMA, same structure.
__global__ __launch_bounds__(256) void k_lin_mfma(
    const unsigned short* __restrict__ H,
    const unsigned short* __restrict__ Wb,
    const float* __restrict__ lb,
    float* __restrict__ x1a) {
  __shared__ unsigned short As[128 * 32];
  __shared__ unsigned short Bs[128 * 32];
  const int bn = blockIdx.x * 128;
  const int bm = blockIdx.y * 128;
  const int tid = threadIdx.x;
  const int lane = tid & 63, wv = tid >> 6;
  const int wr = (wv >> 1) * 64, wc = (wv & 1) * 64;
  f32x4 acc[4][4] = {};

  const int chunk = wv * 2;
  const int rloc = chunk * 16 + (lane >> 2);
  const int slot = (lane & 3) * 8;
  const size_t abase = ((size_t)(bm + rloc)) * NF + slot;
  const size_t bbase = ((size_t)(bn + rloc)) * NF + slot;
  unsigned short* AsW0 = &As[chunk * 512];
  unsigned short* AsW1 = &As[(chunk + 1) * 512];
  unsigned short* BsW0 = &Bs[chunk * 512];
  unsigned short* BsW1 = &Bs[(chunk + 1) * 512];

  const int rsel = lane & 15, ksel = (lane >> 4) * 8;

  for (int kt = 0; kt < NF; kt += 32) {
    GLOAD16(H + abase + kt, AsW0);
    GLOAD16(H + abase + kt + (size_t)16 * NF, AsW1);
    GLOAD16(Wb + bbase + kt, BsW0);
    GLOAD16(Wb + bbase + kt + (size_t)16 * NF, BsW1);
    __syncthreads();
    bf16x8 af[4], bfr[4];
#pragma unroll
    for (int m = 0; m < 4; ++m)
      af[m] = *(const bf16x8*)&As[(wr + m * 16 + rsel) * 32 + ksel];
#pragma unroll
    for (int n = 0; n < 4; ++n)
      bfr[n] = *(const bf16x8*)&Bs[(wc + n * 16 + rsel) * 32 + ksel];
#pragma unroll
    for (int m = 0; m < 4; ++m)
#pragma unroll
      for (int n = 0; n < 4; ++n)
        acc[m][n] = __builtin_amdgcn_mfma_f32_16x16x32_bf16(af[m], bfr[n], acc[m][n], 0, 0, 0);
    __syncthreads();
  }

  const int col0 = bn + wc + (lane & 15);
  const int row0 = bm + wr + (lane >> 4) * 4;
#pragma unroll
  for (int m = 0; m < 4; ++m) {
#pragma unroll
    for (int n = 0; n < 4; ++n) {
      int col = col0 + n * 16;
      float lbv = lb[col];
#pragma unroll
      for (int r = 0; r < 4; ++r) {
        int row = row0 + m * 16 + r;
        size_t oi = (size_t)row * NC + col;
        x1a[oi] = acc[m][n][r] + lbv + x1a[oi];
      }
    }
  }
}

// Windowed cross-attention, MFMA flash-style.
// Block = 64 queries x one (b,h); 4 waves x 16 queries each. 128-key shared window.
// LDS: [0,24576) shorts = K window [128][192] then VT window [192][128] (reused);
//      [24576,32768) = P [4 waves][16][128] bf16. All XOR-granule swizzled.
__global__ __launch_bounds__(256) void k_attn_mfma(
    const unsigned short* __restrict__ qbb,   // [8*2048][384] bf16 (q*scaling)
    const unsigned short* __restrict__ kbb,   // [8*512][384] bf16
    const unsigned short* __restrict__ vtb,   // [(b*2+h)*192+d][512] bf16
    float* __restrict__ o, int guided, float* __restrict__ gl) {
  __shared__ unsigned short lds[32768];
  const int tid = threadIdx.x;
  const int lane = tid & 63, wv = tid >> 6;
  const int rsel = lane & 15, ghi = lane >> 4;
  const int idx = blockIdx.x;
  const int tg = idx & 31;
  const int bh = idx >> 5;
  const int h = bh & 1, b = bh >> 1;
  const int t0 = tg * 64;
  const int c0 = t0 >> 2;
  int klo = c0 - 51; if (klo < 0) klo = 0;
  klo &= ~7;                       // 16B-align for global_load_lds on vtb
  if (klo > 384) klo = 384;        // keep window inside [0,512)

  // Q fragments: A-operand layout, row = lane&15, k = ghi*8 (+32 per step)
  const unsigned short* qrow = qbb + (size_t)(b * NT1 + t0 + wv * 16 + rsel) * NC + h * ND;
  bf16x8 qf[6];
#pragma unroll
  for (int kk = 0; kk < 6; ++kk)
    qf[kk] = *(const bf16x8*)(qrow + kk * 32 + ghi * 8);

  // stage K window [128 keys][192] bf16, source pre-swizzled (granule ^ row&7)
  {
    const size_t kbase = (size_t)(b * NT2 + klo) * NC + h * ND;
#pragma unroll
    for (int it = 0; it < 12; ++it) {
      int g = it * 256 + tid;
      int row = g / 24, go = g % 24;
      int gs = go ^ (row & 7);
      GLOAD16(kbb + kbase + (size_t)row * NC + gs * 8, &lds[(it * 256 + wv * 64) * 8]);
    }
  }
  __syncthreads();

  // QK^T: 16 queries x 128 keys per wave
  f32x4 accs[8] = {};
#pragma unroll
  for (int kk = 0; kk < 6; ++kk) {
#pragma unroll
    for (int n = 0; n < 8; ++n) {
      int row = n * 16 + rsel;
      bf16x8 bfr = *(const bf16x8*)&lds[row * 192 + (((kk * 4 + ghi) ^ (rsel & 7)) * 8)];
      accs[n] = __builtin_amdgcn_mfma_f32_16x16x32_bf16(qf[kk], bfr, accs[n], 0, 0, 0);
    }
  }

  // masked softmax per query row; rows live on 16-lane groups (row=ghi*4+r, col=rsel)
  unsigned short* pl = &lds[24576 + wv * 2048];
  float gacc = 0.f;
  const int t0w = t0 + wv * 16;
#pragma unroll
  for (int r = 0; r < 4; ++r) {
    int t = t0w + ghi * 4 + r;
    int c = t >> 2;
    int loq = c - 51; if (loq < 0) loq = 0;
    int hiq = c + 51; if (hiq > NT2) hiq = NT2;
    float sv[8];
    float mx = -1e30f;
#pragma unroll
    for (int n = 0; n < 8; ++n) {
      int j = klo + n * 16 + rsel;
      float s = (j >= loq && j < hiq) ? accs[n][r] : -1e30f;
      sv[n] = s; mx = fmaxf(mx, s);
    }
#pragma unroll
    for (int off = 1; off < 16; off <<= 1) mx = fmaxf(mx, __shfl_xor(mx, off));
    float e[8]; float se = 0.f;
#pragma unroll
    for (int n = 0; n < 8; ++n) { e[n] = __expf(sv[n] - mx); se += e[n]; }
#pragma unroll
    for (int off = 1; off < 16; off <<= 1) se += __shfl_xor(se, off);
    float inv = 1.f / se;
    int q = ghi * 4 + r;
#pragma unroll
    for (int n = 0; n < 8; ++n) {
      float pv = e[n] * inv;
      int klocal = n * 16 + rsel;
      pl[q * 128 + (((klocal >> 3) ^ (q & 7)) * 8) + (klocal & 7)] = f2bf(pv);
      if (guided) {
        int j = klo + klocal;
        float d = (float)j * (1.f / NT2) - (float)t * (1.f / NT1);
        gacc += pv * (1.f - __expf(-(d * d) * 5.5555555556f));
      }
    }
  }
  if (guided) {
    gacc = warp_sum(gacc);
    if (lane == 0) atomicAdd(gl, gacc * (1.f / 16777216.f));
  }
  __syncthreads();

  // stage VT window [192 chans][128 keys] bf16 into the K buffer (reuse)
  {
    const size_t vbase = ((size_t)(b * 2 + h) * ND) * NT2 + klo;
#pragma unroll
    for (int it = 0; it < 12; ++it) {
      int g = it * 256 + tid;
      int row = g >> 4, go = g & 15;
      int gs = go ^ (row & 7);
      GLOAD16(vtb + vbase + (size_t)row * NT2 + gs * 8, &lds[(it * 256 + wv * 64) * 8]);
    }
  }
  __syncthreads();

  // PV: P[16x128] @ V[128x192] -> O[16x192]
  f32x4 acco[12] = {};
#pragma unroll
  for (int kt = 0; kt < 4; ++kt) {
    bf16x8 pa = *(const bf16x8*)&pl[rsel * 128 + (((kt * 4 + ghi) ^ (rsel & 7)) * 8)];
#pragma unroll
    for (int n = 0; n < 12; ++n) {
      int row = n * 16 + rsel;
      bf16x8 bfr = *(const bf16x8*)&lds[row * 128 + (((kt * 4 + ghi) ^ (rsel & 7)) * 8)];
      acco[n] = __builtin_amdgcn_mfma_f32_16x16x32_bf16(pa, bfr, acco[n], 0, 0, 0);
    }
  }

  float* obase = o + (size_t)(b * NT1 + t0w + ghi * 4) * NC + h * ND;
#pragma unroll
  for (int n = 0; n < 12; ++n) {
#pragma unroll
    for (int r = 0; r < 4; ++r) {
      obase[(size_t)r * NC + n * 16 + rsel] = acco[n][r];
    }
  }
}

extern "C" void kernel_launch(void* const* d_in, const int* in_sizes, int n_in,
                              void* d_out, int out_size, void* d_ws, size_t ws_size,
                              hipStream_t stream) {
  (void)in_sizes; (void)n_in; (void)out_size; (void)ws_size;
  const float* x1    = (const float*)d_in[0];
  const float* x2    = (const float*)d_in[1];
  const float* alpha = (const float*)d_in[2];
  const float* ln1_g = (const float*)d_in[3];
  const float* ln1_b = (const float*)d_in[4];
  const float* qw    = (const float*)d_in[5];
  const float* kw    = (const float*)d_in[6];
  const float* vw    = (const float*)d_in[7];
  const float* ow    = (const float*)d_in[8];
  const float* ln2_g = (const float*)d_in[9];
  const float* ln2_b = (const float*)d_in[10];
  const float* cw    = (const float*)d_in[11];
  const float* cb    = (const float*)d_in[12];
  const float* lw    = (const float*)d_in[13];
  const float* lb    = (const float*)d_in[14];
  const float* lnf_g = (const float*)d_in[15];
  const float* lnf_b = (const float*)d_in[16];
  float* out = (float*)d_out;
  float* gl = out + 6291456;   // guided-loss scalar slot

  float* p = (float*)d_ws;
  float* x1a = p; p += 6291456;    // x1 state [16384,384] f32
  float* x2a = p; p += 1572864;    // x2 + pos [4096,384] f32
  float* tmp = p; p += 6291456;    // LN1 out / attn out f32
  // bf16 region (16B-aligned: 14155776 floats so far)
  unsigned short* us = (unsigned short*)p;
  unsigned short* ypad = us; us += 8 * TPAD * NC;      // 6316032
  unsigned short* cwpb = us; us += (size_t)NF * NKI;   // 5308416
  unsigned short* lwb  = us; us += (size_t)NC * NF;    // 589824
  unsigned short* hb   = us; us += (size_t)16384 * NF; // 25165824
  unsigned short* qbb  = us; us += 6291456;            // q bf16 [16384][384]
  unsigned short* kbb  = us; us += 1572864;            // k bf16 [4096][384]
  unsigned short* vbb  = us; us += 1572864;            // v bf16 [4096][384]
  unsigned short* vtb  = us; us += 1572864;            // v^T bf16 [32*192][512]

  hipMemsetAsync(gl, 0, sizeof(float), stream);  // atomic accumulator, re-zeroed every launch
  k_zero_guard<<<96, 256, 0, stream>>>(ypad);
  k_add_pos<<<24576, 256, 0, stream>>>(x1, alpha, x1a, NT1, 6291456);
  k_add_pos<<<6144, 256, 0, stream>>>(x2, alpha, x2a, NT2, 1572864);

  const float scaling = 0.07216878364870323f;   // 192^-0.5
  for (int l = 0; l < 2; ++l) {
    k_ln<<<4096, 256, 0, stream>>>(x1a, ln1_g + l * 384, ln1_b + l * 384, tmp, 16384);
    k_gemm<<<dim3(6, 256), 256, 0, stream>>>(tmp, qw + (size_t)l * 147456, nullptr, qbb,
                                             nullptr, nullptr, 16384, 384, 384, scaling);
    k_gemm<<<dim3(6, 64), 256, 0, stream>>>(x2a, kw + (size_t)l * 147456, nullptr, kbb,
                                            nullptr, nullptr, 4096, 384, 384, 1.f);
    k_gemm<<<dim3(6, 64), 256, 0, stream>>>(x2a, vw + (size_t)l * 147456, nullptr, vbb,
                                            nullptr, nullptr, 4096, 384, 384, 1.f);
    k_vt<<<6144, 256, 0, stream>>>(vbb, vtb);
    k_attn_mfma<<<512, 256, 0, stream>>>(qbb, kbb, vtb, tmp, l == 0 ? 1 : 0, gl);
    k_gemm<<<dim3(6, 256), 256, 0, stream>>>(tmp, ow + (size_t)l * 147456, x1a, nullptr,
                                             nullptr, x1a, 16384, 384, 384, 1.f);
    // FFN: ln2 -> bf16 padded, conv implicit GEMM (MFMA), linear (MFMA)
    k_ln_bf16p<<<4096, 256, 0, stream>>>(x1a, ln2_g + l * 384, ln2_b + l * 384, ypad);
    k_pack_cw_bf16<<<20736, 256, 0, stream>>>(cw + (size_t)l * 5308416, cwpb);
    k_cvt_bf16<<<2304, 256, 0, stream>>>(lw + (size_t)l * 589824, lwb, 589824);
    k_conv_mfma<<<dim3(12, 128), 256, 0, stream>>>(ypad, cwpb, cb + l * 1536, hb);
    k_lin_mfma<<<dim3(3, 128), 256, 0, stream>>>(hb, lwb, lb + l * 384, x1a);
  }
  k_ln<<<4096, 256, 0, stream>>>(x1a, lnf_g, lnf_b, out, 16384);
}

// Round 2
// 802.014 us; speedup vs baseline: 2.5997x; 1.5899x over previous
//
#include <hip/hip_runtime.h>
#include <math.h>

#define NB 8
#define NT1 2048
#define NT2 512
#define NC 384
#define ND 192
#define NF 1536
#define NKI 3456   // 9*384 implicit-GEMM K for conv
#define TPAD 2056  // 2048 + 4 guard rows top and bottom

typedef __attribute__((ext_vector_type(8))) short bf16x8;
typedef __attribute__((ext_vector_type(4))) float f32x4;

#define GLOAD16(gsrc, ldst) \
  __builtin_amdgcn_global_load_lds((const __attribute__((address_space(1))) void*)(gsrc), \
                                   (__attribute__((address_space(3))) void*)(ldst), 16, 0, 0)

static __device__ __forceinline__ unsigned short f2bf(float f) {
  unsigned int u = __float_as_uint(f);
  unsigned int r = (u + 0x7fffu + ((u >> 16) & 1u)) >> 16;
  return (unsigned short)r;
}

static __device__ __forceinline__ float warp_sum(float v) {
#pragma unroll
  for (int off = 32; off > 0; off >>= 1) v += __shfl_xor(v, off);
  return v;
}

// x += alpha * sinusoidal positional embedding (fairseq style, pos = t+1), fp32 out
__global__ __launch_bounds__(256) void k_add_pos(const float* __restrict__ x,
    const float* __restrict__ alpha_p, float* __restrict__ y, int T, int total) {
  int i = blockIdx.x * 256 + threadIdx.x;
  if (i >= total) return;
  int c = i % NC;
  int t = (i / NC) % T;
  int j = (c < 192) ? c : (c - 192);
  float freq = expf(-0.0482216773f * (float)j);   // ln(10000)/191
  float ang = (float)(t + 1) * freq;
  float sp = (c < 192) ? sinf(ang) : cosf(ang);
  y[i] = x[i] + alpha_p[0] * sp;
}

// same, bf16 out (x2 path feeds bf16 MFMA projections only)
__global__ __launch_bounds__(256) void k_add_pos_bf16(const float* __restrict__ x,
    const float* __restrict__ alpha_p, unsigned short* __restrict__ y, int T, int total) {
  int i = blockIdx.x * 256 + threadIdx.x;
  if (i >= total) return;
  int c = i % NC;
  int t = (i / NC) % T;
  int j = (c < 192) ? c : (c - 192);
  float freq = expf(-0.0482216773f * (float)j);
  float ang = (float)(t + 1) * freq;
  float sp = (c < 192) ? sinf(ang) : cosf(ang);
  y[i] = f2bf(x[i] + alpha_p[0] * sp);
}

// LayerNorm over last dim (384). One wave per row. fp32 out (final LN).
__global__ __launch_bounds__(256) void k_ln(const float* __restrict__ x,
    const float* __restrict__ g, const float* __restrict__ b,
    float* __restrict__ y, int nrows) {
  int row = blockIdx.x * 4 + (threadIdx.x >> 6);
  int lane = threadIdx.x & 63;
  if (row >= nrows) return;
  const float* xr = x + (size_t)row * NC;
  float v[6];
  float s = 0.f, s2 = 0.f;
#pragma unroll
  for (int i = 0; i < 6; ++i) {
    float t = xr[lane + 64 * i];
    v[i] = t; s += t; s2 += t * t;
  }
  s = warp_sum(s); s2 = warp_sum(s2);
  float mean = s * (1.f / NC);
  float var = s2 * (1.f / NC) - mean * mean;
  float rs = rsqrtf(var + 1e-5f);
  float* yr = y + (size_t)row * NC;
#pragma unroll
  for (int i = 0; i < 6; ++i) {
    int cc = lane + 64 * i;
    yr[cc] = (v[i] - mean) * rs * g[cc] + b[cc];
  }
}

// LayerNorm -> bf16 (unpadded), feeds MFMA projections
__global__ __launch_bounds__(256) void k_ln_bf16(const float* __restrict__ x,
    const float* __restrict__ g, const float* __restrict__ b,
    unsigned short* __restrict__ y) {
  int row = blockIdx.x * 4 + (threadIdx.x >> 6);
  int lane = threadIdx.x & 63;
  const float* xr = x + (size_t)row * NC;
  float v[6];
  float s = 0.f, s2 = 0.f;
#pragma unroll
  for (int i = 0; i < 6; ++i) {
    float t = xr[lane + 64 * i];
    v[i] = t; s += t; s2 += t * t;
  }
  s = warp_sum(s); s2 = warp_sum(s2);
  float mean = s * (1.f / NC);
  float var = s2 * (1.f / NC) - mean * mean;
  float rs = rsqrtf(var + 1e-5f);
  unsigned short* yr = y + (size_t)row * NC;
#pragma unroll
  for (int i = 0; i < 6; ++i) {
    int cc = lane + 64 * i;
    yr[cc] = f2bf((v[i] - mean) * rs * g[cc] + b[cc]);
  }
}

// LayerNorm -> bf16 into guard-padded [8][2056][384] buffer (row t -> t+4)
__global__ __launch_bounds__(256) void k_ln_bf16p(const float* __restrict__ x,
    const float* __restrict__ g, const float* __restrict__ b,
    unsigned short* __restrict__ ypad) {
  int row = blockIdx.x * 4 + (threadIdx.x >> 6);
  int lane = threadIdx.x & 63;
  const float* xr = x + (size_t)row * NC;
  float v[6];
  float s = 0.f, s2 = 0.f;
#pragma unroll
  for (int i = 0; i < 6; ++i) {
    float t = xr[lane + 64 * i];
    v[i] = t; s += t; s2 += t * t;
  }
  s = warp_sum(s); s2 = warp_sum(s2);
  float mean = s * (1.f / NC);
  float var = s2 * (1.f / NC) - mean * mean;
  float rs = rsqrtf(var + 1e-5f);
  int bb = row >> 11, t = row & 2047;
  unsigned short* yr = ypad + ((size_t)(bb * TPAD + t + 4)) * NC;
#pragma unroll
  for (int i = 0; i < 6; ++i) {
    int cc = lane + 64 * i;
    yr[cc] = f2bf((v[i] - mean) * rs * g[cc] + b[cc]);
  }
}

// zero the 4 guard rows top+bottom of each batch slab in ypad
__global__ __launch_bounds__(256) void k_zero_guard(unsigned short* __restrict__ ypad) {
  int i = blockIdx.x * 256 + threadIdx.x;   // 8*8*384 = 24576
  if (i >= 24576) return;
  int c = i % NC;
  int r = (i / NC) % 8;
  int b = i / (NC * 8);
  int t = (r < 4) ? r : (2048 + r);         // rows 0..3 and 2052..2055
  ypad[((size_t)b * TPAD + t) * NC + c] = 0;
}

// pack + convert cw[f][c][kk] -> cwp[f][kk*384+c] bf16 (both layers, n = 2*NF*NKI)
__global__ __launch_bounds__(256) void k_pack_cw_bf16(const float* __restrict__ cw,
    unsigned short* __restrict__ cwp, int n) {
  int i = blockIdx.x * 256 + threadIdx.x;
  if (i >= n) return;
  int cc = i % NC;
  int kk = (i / NC) % 9;
  int f = i / NKI;
  cwp[i] = f2bf(cw[(size_t)f * NKI + cc * 9 + kk]);
}

// fp32 -> bf16 with scale (scale folds q's 192^-0.5 into qw)
__global__ __launch_bounds__(256) void k_cvt_scale(const float* __restrict__ x,
    unsigned short* __restrict__ y, int n, float scale) {
  int i = blockIdx.x * 256 + threadIdx.x;
  if (i < n) y[i] = f2bf(x[i] * scale);
}

// V transpose: vbb [b*512+j][h*192+d] bf16 -> vtb [(b*2+h)*192+d][512 j] bf16
__global__ __launch_bounds__(256) void k_vt(const unsigned short* __restrict__ vbb,
    unsigned short* __restrict__ vtb) {
  int i = blockIdx.x * 256 + threadIdx.x;   // 8*2*192*512 = 1572864
  if (i >= 1572864) return;
  int j = i & 511;
  int i2 = i >> 9;
  int d = i2 % 192;
  int bh = i2 / 192;
  int b = bh >> 1, h = bh & 1;
  vtb[i] = vbb[(size_t)(b * 512 + j) * NC + h * ND + d];
}

// Projection GEMM: A[M,K]bf16 @ W[N=384,K]bf16^T. 128x128 tile, m97 structure.
// If Cb: write bf16 C[M,384]. Else: Cf[M,384] += acc (fused residual, o-proj).
__global__ __launch_bounds__(256) void k_pgemm_mfma(
    const unsigned short* __restrict__ A,
    const unsigned short* __restrict__ W,
    unsigned short* __restrict__ Cb,
    float* __restrict__ Cf,
    int K) {
  __shared__ unsigned short As[128 * 32];
  __shared__ unsigned short Bs[128 * 32];
  const int bn = blockIdx.x * 128;
  const int bm = blockIdx.y * 128;
  const int tid = threadIdx.x;
  const int lane = tid & 63, wv = tid >> 6;
  const int wr = (wv >> 1) * 64, wc = (wv & 1) * 64;
  f32x4 acc[4][4] = {};

  const int chunk = wv * 2;
  const int rloc = chunk * 16 + (lane >> 2);
  const int slot = (lane & 3) * 8;
  const size_t abase = ((size_t)(bm + rloc)) * K + slot;
  const size_t bbase = ((size_t)(bn + rloc)) * K + slot;
  unsigned short* AsW0 = &As[chunk * 512];
  unsigned short* AsW1 = &As[(chunk + 1) * 512];
  unsigned short* BsW0 = &Bs[chunk * 512];
  unsigned short* BsW1 = &Bs[(chunk + 1) * 512];

  const int rsel = lane & 15, ksel = (lane >> 4) * 8;

  for (int kt = 0; kt < K; kt += 32) {
    GLOAD16(A + abase + kt, AsW0);
    GLOAD16(A + abase + kt + (size_t)16 * K, AsW1);
    GLOAD16(W + bbase + kt, BsW0);
    GLOAD16(W + bbase + kt + (size_t)16 * K, BsW1);
    __syncthreads();
    bf16x8 af[4], bfr[4];
#pragma unroll
    for (int m = 0; m < 4; ++m)
      af[m] = *(const bf16x8*)&As[(wr + m * 16 + rsel) * 32 + ksel];
#pragma unroll
    for (int n = 0; n < 4; ++n)
      bfr[n] = *(const bf16x8*)&Bs[(wc + n * 16 + rsel) * 32 + ksel];
#pragma unroll
    for (int m = 0; m < 4; ++m)
#pragma unroll
      for (int n = 0; n < 4; ++n)
        acc[m][n] = __builtin_amdgcn_mfma_f32_16x16x32_bf16(af[m], bfr[n], acc[m][n], 0, 0, 0);
    __syncthreads();
  }

  const int col0 = bn + wc + (lane & 15);
  const int row0 = bm + wr + (lane >> 4) * 4;
#pragma unroll
  for (int m = 0; m < 4; ++m) {
#pragma unroll
    for (int n = 0; n < 4; ++n) {
      int col = col0 + n * 16;
#pragma unroll
      for (int r = 0; r < 4; ++r) {
        int row = row0 + m * 16 + r;
        size_t oi = (size_t)row * NC + col;
        if (Cb) Cb[oi] = f2bf(acc[m][n][r]);
        else Cf[oi] = acc[m][n][r] + Cf[oi];
      }
    }
  }
}

// Conv1d(C->4C,k=9,SAME) implicit GEMM, bf16 MFMA 128x128xBK32 (m97 structure),
// fused (+cb)*9^-0.5 -> gelu(exact) -> bf16 store.
// Grid: x = bm (fast, 128), y = bn (12) so the Wp panel stays L2-hot per XCD.
__global__ __launch_bounds__(256) void k_conv_mfma(
    const unsigned short* __restrict__ Ypad,
    const unsigned short* __restrict__ Wp,
    const float* __restrict__ cb,
    unsigned short* __restrict__ H) {
  __shared__ unsigned short As[128 * 32];
  __shared__ unsigned short Bs[128 * 32];
  const int bn = blockIdx.y * 128;
  const int bm = blockIdx.x * 128;
  const int b = bm >> 11, t0 = bm & 2047;
  const int tid = threadIdx.x;
  const int lane = tid & 63, wv = tid >> 6;
  const int wr = (wv >> 1) * 64, wc = (wv & 1) * 64;
  f32x4 acc[4][4] = {};

  const int chunk = wv * 2;
  const int rloc = chunk * 16 + (lane >> 2);
  const int slot = (lane & 3) * 8;
  const size_t abase = ((size_t)(b * TPAD + t0 + rloc)) * NC + slot;
  const size_t bbase = ((size_t)(bn + rloc)) * NKI + slot;
  unsigned short* AsW0 = &As[chunk * 512];
  unsigned short* AsW1 = &As[(chunk + 1) * 512];
  unsigned short* BsW0 = &Bs[chunk * 512];
  unsigned short* BsW1 = &Bs[(chunk + 1) * 512];

  const int rsel = lane & 15, ksel = (lane >> 4) * 8;

  for (int kt = 0; kt < NKI; kt += 32) {
    const int kk = kt / NC;
    const int c0 = kt - kk * NC;
    const size_t aoff = (size_t)kk * NC + c0;
    GLOAD16(Ypad + abase + aoff, AsW0);
    GLOAD16(Ypad + abase + aoff + (size_t)16 * NC, AsW1);
    GLOAD16(Wp + bbase + kt, BsW0);
    GLOAD16(Wp + bbase + kt + (size_t)16 * NKI, BsW1);
    __syncthreads();
    bf16x8 af[4], bfr[4];
#pragma unroll
    for (int m = 0; m < 4; ++m)
      af[m] = *(const bf16x8*)&As[(wr + m * 16 + rsel) * 32 + ksel];
#pragma unroll
    for (int n = 0; n < 4; ++n)
      bfr[n] = *(const bf16x8*)&Bs[(wc + n * 16 + rsel) * 32 + ksel];
#pragma unroll
    for (int m = 0; m < 4; ++m)
#pragma unroll
      for (int n = 0; n < 4; ++n)
        acc[m][n] = __builtin_amdgcn_mfma_f32_16x16x32_bf16(af[m], bfr[n], acc[m][n], 0, 0, 0);
    __syncthreads();
  }

  const int col0 = bn + wc + (lane & 15);
  const int row0 = bm + wr + (lane >> 4) * 4;
#pragma unroll
  for (int m = 0; m < 4; ++m) {
#pragma unroll
    for (int n = 0; n < 4; ++n) {
      int col = col0 + n * 16;
      float cbv = cb[col];
#pragma unroll
      for (int r = 0; r < 4; ++r) {
        int row = row0 + m * 16 + r;
        float xv = (acc[m][n][r] + cbv) * 0.33333333333333333f;
        float ge = 0.5f * xv * (1.f + erff(xv * 0.70710678118654752f));
        H[(size_t)row * NF + col] = f2bf(ge);
      }
    }
  }
}

// FFN linear: x1a[m][n] += H[m][:]@lw[n][:] + lb[n].  bf16 MFMA, same structure.
__global__ __launch_bounds__(256) void k_lin_mfma(
    const unsigned short* __restrict__ H,
    const unsigned short* __restrict__ Wb,
    const float* __restrict__ lb,
    float* __restrict__ x1a) {
  __shared__ unsigned short As[128 * 32];
  __shared__ unsigned short Bs[128 * 32];
  const int bn = blockIdx.x * 128;
  const int bm = blockIdx.y * 128;
  const int tid = threadIdx.x;
  const int lane = tid & 63, wv = tid >> 6;
  const int wr = (wv >> 1) * 64, wc = (wv & 1) * 64;
  f32x4 acc[4][4] = {};

  const int chunk = wv * 2;
  const int rloc = chunk * 16 + (lane >> 2);
  const int slot = (lane & 3) * 8;
  const size_t abase = ((size_t)(bm + rloc)) * NF + slot;
  const size_t bbase = ((size_t)(bn + rloc)) * NF + slot;
  unsigned short* AsW0 = &As[chunk * 512];
  unsigned short* AsW1 = &As[(chunk + 1) * 512];
  unsigned short* BsW0 = &Bs[chunk * 512];
  unsigned short* BsW1 = &Bs[(chunk + 1) * 512];

  const int rsel = lane & 15, ksel = (lane >> 4) * 8;

  for (int kt = 0; kt < NF; kt += 32) {
    GLOAD16(H + abase + kt, AsW0);
    GLOAD16(H + abase + kt + (size_t)16 * NF, AsW1);
    GLOAD16(Wb + bbase + kt, BsW0);
    GLOAD16(Wb + bbase + kt + (size_t)16 * NF, BsW1);
    __syncthreads();
    bf16x8 af[4], bfr[4];
#pragma unroll
    for (int m = 0; m < 4; ++m)
      af[m] = *(const bf16x8*)&As[(wr + m * 16 + rsel) * 32 + ksel];
#pragma unroll
    for (int n = 0; n < 4; ++n)
      bfr[n] = *(const bf16x8*)&Bs[(wc + n * 16 + rsel) * 32 + ksel];
#pragma unroll
    for (int m = 0; m < 4; ++m)
#pragma unroll
      for (int n = 0; n < 4; ++n)
        acc[m][n] = __builtin_amdgcn_mfma_f32_16x16x32_bf16(af[m], bfr[n], acc[m][n], 0, 0, 0);
    __syncthreads();
  }

  const int col0 = bn + wc + (lane & 15);
  const int row0 = bm + wr + (lane >> 4) * 4;
#pragma unroll
  for (int m = 0; m < 4; ++m) {
#pragma unroll
    for (int n = 0; n < 4; ++n) {
      int col = col0 + n * 16;
      float lbv = lb[col];
#pragma unroll
      for (int r = 0; r < 4; ++r) {
        int row = row0 + m * 16 + r;
        size_t oi = (size_t)row * NC + col;
        x1a[oi] = acc[m][n][r] + lbv + x1a[oi];
      }
    }
  }
}

// Windowed cross-attention, MFMA flash-style. bf16 output (feeds o-projection).
__global__ __launch_bounds__(256) void k_attn_mfma(
    const unsigned short* __restrict__ qbb,   // [8*2048][384] bf16 (q*scaling folded in W)
    const unsigned short* __restrict__ kbb,   // [8*512][384] bf16
    const unsigned short* __restrict__ vtb,   // [(b*2+h)*192+d][512] bf16
    unsigned short* __restrict__ o, int guided, float* __restrict__ gl) {
  __shared__ unsigned short lds[32768];
  const int tid = threadIdx.x;
  const int lane = tid & 63, wv = tid >> 6;
  const int rsel = lane & 15, ghi = lane >> 4;
  const int idx = blockIdx.x;
  const int tg = idx & 31;
  const int bh = idx >> 5;
  const int h = bh & 1, b = bh >> 1;
  const int t0 = tg * 64;
  const int c0 = t0 >> 2;
  int klo = c0 - 51; if (klo < 0) klo = 0;
  klo &= ~7;                       // 16B-align for global_load_lds on vtb
  if (klo > 384) klo = 384;        // keep window inside [0,512)

  // Q fragments: A-operand layout, row = lane&15, k = ghi*8 (+32 per step)
  const unsigned short* qrow = qbb + (size_t)(b * NT1 + t0 + wv * 16 + rsel) * NC + h * ND;
  bf16x8 qf[6];
#pragma unroll
  for (int kk = 0; kk < 6; ++kk)
    qf[kk] = *(const bf16x8*)(qrow + kk * 32 + ghi * 8);

  // stage K window [128 keys][192] bf16, source pre-swizzled (granule ^ row&7)
  {
    const size_t kbase = (size_t)(b * NT2 + klo) * NC + h * ND;
#pragma unroll
    for (int it = 0; it < 12; ++it) {
      int g = it * 256 + tid;
      int row = g / 24, go = g % 24;
      int gs = go ^ (row & 7);
      GLOAD16(kbb + kbase + (size_t)row * NC + gs * 8, &lds[(it * 256 + wv * 64) * 8]);
    }
  }
  __syncthreads();

  // QK^T: 16 queries x 128 keys per wave
  f32x4 accs[8] = {};
#pragma unroll
  for (int kk = 0; kk < 6; ++kk) {
#pragma unroll
    for (int n = 0; n < 8; ++n) {
      int row = n * 16 + rsel;
      bf16x8 bfr = *(const bf16x8*)&lds[row * 192 + (((kk * 4 + ghi) ^ (rsel & 7)) * 8)];
      accs[n] = __builtin_amdgcn_mfma_f32_16x16x32_bf16(qf[kk], bfr, accs[n], 0, 0, 0);
    }
  }

  // masked softmax per query row; rows live on 16-lane groups (row=ghi*4+r, col=rsel)
  unsigned short* pl = &lds[24576 + wv * 2048];
  float gacc = 0.f;
  const int t0w = t0 + wv * 16;
#pragma unroll
  for (int r = 0; r < 4; ++r) {
    int t = t0w + ghi * 4 + r;
    int c = t >> 2;
    int loq = c - 51; if (loq < 0) loq = 0;
    int hiq = c + 51; if (hiq > NT2) hiq = NT2;
    float sv[8];
    float mx = -1e30f;
#pragma unroll
    for (int n = 0; n < 8; ++n) {
      int j = klo + n * 16 + rsel;
      float s = (j >= loq && j < hiq) ? accs[n][r] : -1e30f;
      sv[n] = s; mx = fmaxf(mx, s);
    }
#pragma unroll
    for (int off = 1; off < 16; off <<= 1) mx = fmaxf(mx, __shfl_xor(mx, off));
    float e[8]; float se = 0.f;
#pragma unroll
    for (int n = 0; n < 8; ++n) { e[n] = __expf(sv[n] - mx); se += e[n]; }
#pragma unroll
    for (int off = 1; off < 16; off <<= 1) se += __shfl_xor(se, off);
    float inv = 1.f / se;
    int q = ghi * 4 + r;
#pragma unroll
    for (int n = 0; n < 8; ++n) {
      float pv = e[n] * inv;
      int klocal = n * 16 + rsel;
      pl[q * 128 + (((klocal >> 3) ^ (q & 7)) * 8) + (klocal & 7)] = f2bf(pv);
      if (guided) {
        int j = klo + klocal;
        float d = (float)j * (1.f / NT2) - (float)t * (1.f / NT1);
        gacc += pv * (1.f - __expf(-(d * d) * 5.5555555556f));
      }
    }
  }
  if (guided) {
    gacc = warp_sum(gacc);
    if (lane == 0) atomicAdd(gl, gacc * (1.f / 16777216.f));
  }
  __syncthreads();

  // stage VT window [192 chans][128 keys] bf16 into the K buffer (reuse)
  {
    const size_t vbase = ((size_t)(b * 2 + h) * ND) * NT2 + klo;
#pragma unroll
    for (int it = 0; it < 12; ++it) {
      int g = it * 256 + tid;
      int row = g >> 4, go = g & 15;
      int gs = go ^ (row & 7);
      GLOAD16(vtb + vbase + (size_t)row * NT2 + gs * 8, &lds[(it * 256 + wv * 64) * 8]);
    }
  }
  __syncthreads();

  // PV: P[16x128] @ V[128x192] -> O[16x192]
  f32x4 acco[12] = {};
#pragma unroll
  for (int kt = 0; kt < 4; ++kt) {
    bf16x8 pa = *(const bf16x8*)&pl[rsel * 128 + (((kt * 4 + ghi) ^ (rsel & 7)) * 8)];
#pragma unroll
    for (int n = 0; n < 12; ++n) {
      int row = n * 16 + rsel;
      bf16x8 bfr = *(const bf16x8*)&lds[row * 128 + (((kt * 4 + ghi) ^ (rsel & 7)) * 8)];
      acco[n] = __builtin_amdgcn_mfma_f32_16x16x32_bf16(pa, bfr, acco[n], 0, 0, 0);
    }
  }

  unsigned short* obase = o + (size_t)(b * NT1 + t0w + ghi * 4) * NC + h * ND;
#pragma unroll
  for (int n = 0; n < 12; ++n) {
#pragma unroll
    for (int r = 0; r < 4; ++r) {
      obase[(size_t)r * NC + n * 16 + rsel] = f2bf(acco[n][r]);
    }
  }
}

extern "C" void kernel_launch(void* const* d_in, const int* in_sizes, int n_in,
                              void* d_out, int out_size, void* d_ws, size_t ws_size,
                              hipStream_t stream) {
  (void)in_sizes; (void)n_in; (void)out_size; (void)ws_size;
  const float* x1    = (const float*)d_in[0];
  const float* x2    = (const float*)d_in[1];
  const float* alpha = (const float*)d_in[2];
  const float* ln1_g = (const float*)d_in[3];
  const float* ln1_b = (const float*)d_in[4];
  const float* qw    = (const float*)d_in[5];
  const float* kw    = (const float*)d_in[6];
  const float* vw    = (const float*)d_in[7];
  const float* ow    = (const float*)d_in[8];
  const float* ln2_g = (const float*)d_in[9];
  const float* ln2_b = (const float*)d_in[10];
  const float* cw    = (const float*)d_in[11];
  const float* cb    = (const float*)d_in[12];
  const float* lw    = (const float*)d_in[13];
  const float* lb    = (const float*)d_in[14];
  const float* lnf_g = (const float*)d_in[15];
  const float* lnf_b = (const float*)d_in[16];
  float* out = (float*)d_out;
  float* gl = out + 6291456;   // guided-loss scalar slot

  float* p = (float*)d_ws;
  float* x1a = p; p += 6291456;    // x1 state [16384,384] f32
  // bf16 region (16B-aligned: 6291456 floats so far)
  unsigned short* us = (unsigned short*)p;
  unsigned short* x2b  = us; us += 1572864;            // x2+pos bf16 [4096][384]
  unsigned short* tmpb = us; us += 6291456;            // LN1 out / attn out bf16
  unsigned short* ypad = us; us += 8 * TPAD * NC;      // 6316032
  unsigned short* cwpb = us; us += 2 * (size_t)NF * NKI;   // 10616832 (both layers)
  unsigned short* lwb  = us; us += 2 * (size_t)NC * NF;    // 1179648 (both layers)
  unsigned short* hb   = us; us += (size_t)16384 * NF; // 25165824
  unsigned short* qbb  = us; us += 6291456;            // q bf16 [16384][384]
  unsigned short* kbb  = us; us += 1572864;            // k bf16 [4096][384]
  unsigned short* vbb  = us; us += 1572864;            // v bf16 [4096][384]
  unsigned short* vtb  = us; us += 1572864;            // v^T bf16 [32*192][512]
  unsigned short* qwb  = us; us += 294912;             // weights bf16 (2 layers each)
  unsigned short* kwb  = us; us += 294912;
  unsigned short* vwb  = us; us += 294912;
  unsigned short* owb  = us; us += 294912;

  hipMemsetAsync(gl, 0, sizeof(float), stream);  // atomic accumulator, re-zeroed every launch
  k_zero_guard<<<96, 256, 0, stream>>>(ypad);
  k_add_pos<<<24576, 256, 0, stream>>>(x1, alpha, x1a, NT1, 6291456);
  k_add_pos_bf16<<<6144, 256, 0, stream>>>(x2, alpha, x2b, NT2, 1572864);

  const float scaling = 0.07216878364870323f;   // 192^-0.5
  // weight conversions, both layers, hoisted
  k_cvt_scale<<<1152, 256, 0, stream>>>(qw, qwb, 294912, scaling);
  k_cvt_scale<<<1152, 256, 0, stream>>>(kw, kwb, 294912, 1.f);
  k_cvt_scale<<<1152, 256, 0, stream>>>(vw, vwb, 294912, 1.f);
  k_cvt_scale<<<1152, 256, 0, stream>>>(ow, owb, 294912, 1.f);
  k_cvt_scale<<<4608, 256, 0, stream>>>(lw, lwb, 1179648, 1.f);
  k_pack_cw_bf16<<<41472, 256, 0, stream>>>(cw, cwpb, 10616832);

  for (int l = 0; l < 2; ++l) {
    k_ln_bf16<<<4096, 256, 0, stream>>>(x1a, ln1_g + l * 384, ln1_b + l * 384, tmpb);
    k_pgemm_mfma<<<dim3(3, 128), 256, 0, stream>>>(tmpb, qwb + (size_t)l * 147456, qbb, nullptr, 384);
    k_pgemm_mfma<<<dim3(3, 32), 256, 0, stream>>>(x2b, kwb + (size_t)l * 147456, kbb, nullptr, 384);
    k_pgemm_mfma<<<dim3(3, 32), 256, 0, stream>>>(x2b, vwb + (size_t)l * 147456, vbb, nullptr, 384);
    k_vt<<<6144, 256, 0, stream>>>(vbb, vtb);
    k_attn_mfma<<<512, 256, 0, stream>>>(qbb, kbb, vtb, tmpb, l == 0 ? 1 : 0, gl);
    k_pgemm_mfma<<<dim3(3, 128), 256, 0, stream>>>(tmpb, owb + (size_t)l * 147456, nullptr, x1a, 384);
    // FFN: ln2 -> bf16 padded, conv implicit GEMM (MFMA), linear (MFMA)
    k_ln_bf16p<<<4096, 256, 0, stream>>>(x1a, ln2_g + l * 384, ln2_b + l * 384, ypad);
    k_conv_mfma<<<dim3(128, 12), 256, 0, stream>>>(ypad, cwpb + (size_t)l * 5308416, cb + l * 1536, hb);
    k_lin_mfma<<<dim3(3, 128), 256, 0, stream>>>(hb, lwb + (size_t)l * 589824, lb + l * 384, x1a);
  }
  k_ln<<<4096, 256, 0, stream>>>(x1a, lnf_g, lnf_b, out, 16384);
}

// Round 3
// 750.808 us; speedup vs baseline: 2.7770x; 1.0682x over previous
//
#include <hip/hip_runtime.h>
#include <math.h>

#define NB 8
#define NT1 2048
#define NT2 512
#define NC 384
#define ND 192
#define NF 1536
#define NKI 3456   // 9*384 implicit-GEMM K for conv
#define TPAD 2056  // 2048 + 4 guard rows top and bottom

typedef __attribute__((ext_vector_type(8))) short bf16x8;
typedef __attribute__((ext_vector_type(4))) float f32x4;

#define GLOAD16(gsrc, ldst) \
  __builtin_amdgcn_global_load_lds((const __attribute__((address_space(1))) void*)(gsrc), \
                                   (__attribute__((address_space(3))) void*)(ldst), 16, 0, 0)

static __device__ __forceinline__ unsigned short f2bf(float f) {
  unsigned int u = __float_as_uint(f);
  unsigned int r = (u + 0x7fffu + ((u >> 16) & 1u)) >> 16;
  return (unsigned short)r;
}

static __device__ __forceinline__ float warp_sum(float v) {
#pragma unroll
  for (int off = 32; off > 0; off >>= 1) v += __shfl_xor(v, off);
  return v;
}

// x += alpha * sin-pos; thread handles (t,j) pair: sin at c=j, cos at c=j+192
__global__ __launch_bounds__(256) void k_add_pos2(const float* __restrict__ x,
    const float* __restrict__ alpha_p, float* __restrict__ y, int T, int total2) {
  int i = blockIdx.x * 256 + threadIdx.x;
  if (i >= total2) return;
  int j = i % 192;
  int row = i / 192;
  int t = row % T;
  float freq = __expf(-0.0482216773f * (float)j);   // ln(10000)/191
  float ang = (float)(t + 1) * freq;
  float sn, cs;
  __sincosf(ang, &sn, &cs);
  float a = alpha_p[0];
  size_t base = (size_t)row * NC;
  y[base + j] = x[base + j] + a * sn;
  y[base + j + 192] = x[base + j + 192] + a * cs;
}

__global__ __launch_bounds__(256) void k_add_pos2_bf16(const float* __restrict__ x,
    const float* __restrict__ alpha_p, unsigned short* __restrict__ y, int T, int total2) {
  int i = blockIdx.x * 256 + threadIdx.x;
  if (i >= total2) return;
  int j = i % 192;
  int row = i / 192;
  int t = row % T;
  float freq = __expf(-0.0482216773f * (float)j);
  float ang = (float)(t + 1) * freq;
  float sn, cs;
  __sincosf(ang, &sn, &cs);
  float a = alpha_p[0];
  size_t base = (size_t)row * NC;
  y[base + j] = f2bf(x[base + j] + a * sn);
  y[base + j + 192] = f2bf(x[base + j + 192] + a * cs);
}

// LayerNorm over last dim (384). One wave per row. fp32 out (final LN).
__global__ __launch_bounds__(256) void k_ln(const float* __restrict__ x,
    const float* __restrict__ g, const float* __restrict__ b,
    float* __restrict__ y, int nrows) {
  int row = blockIdx.x * 4 + (threadIdx.x >> 6);
  int lane = threadIdx.x & 63;
  if (row >= nrows) return;
  const float* xr = x + (size_t)row * NC;
  float v[6];
  float s = 0.f, s2 = 0.f;
#pragma unroll
  for (int i = 0; i < 6; ++i) {
    float t = xr[lane + 64 * i];
    v[i] = t; s += t; s2 += t * t;
  }
  s = warp_sum(s); s2 = warp_sum(s2);
  float mean = s * (1.f / NC);
  float var = s2 * (1.f / NC) - mean * mean;
  float rs = rsqrtf(var + 1e-5f);
  float* yr = y + (size_t)row * NC;
#pragma unroll
  for (int i = 0; i < 6; ++i) {
    int cc = lane + 64 * i;
    yr[cc] = (v[i] - mean) * rs * g[cc] + b[cc];
  }
}

// LayerNorm -> bf16 (unpadded), feeds MFMA projections
__global__ __launch_bounds__(256) void k_ln_bf16(const float* __restrict__ x,
    const float* __restrict__ g, const float* __restrict__ b,
    unsigned short* __restrict__ y) {
  int row = blockIdx.x * 4 + (threadIdx.x >> 6);
  int lane = threadIdx.x & 63;
  const float* xr = x + (size_t)row * NC;
  float v[6];
  float s = 0.f, s2 = 0.f;
#pragma unroll
  for (int i = 0; i < 6; ++i) {
    float t = xr[lane + 64 * i];
    v[i] = t; s += t; s2 += t * t;
  }
  s = warp_sum(s); s2 = warp_sum(s2);
  float mean = s * (1.f / NC);
  float var = s2 * (1.f / NC) - mean * mean;
  float rs = rsqrtf(var + 1e-5f);
  unsigned short* yr = y + (size_t)row * NC;
#pragma unroll
  for (int i = 0; i < 6; ++i) {
    int cc = lane + 64 * i;
    yr[cc] = f2bf((v[i] - mean) * rs * g[cc] + b[cc]);
  }
}

// LayerNorm -> bf16 into guard-padded [8][2056][384] buffer (row t -> t+4)
__global__ __launch_bounds__(256) void k_ln_bf16p(const float* __restrict__ x,
    const float* __restrict__ g, const float* __restrict__ b,
    unsigned short* __restrict__ ypad) {
  int row = blockIdx.x * 4 + (threadIdx.x >> 6);
  int lane = threadIdx.x & 63;
  const float* xr = x + (size_t)row * NC;
  float v[6];
  float s = 0.f, s2 = 0.f;
#pragma unroll
  for (int i = 0; i < 6; ++i) {
    float t = xr[lane + 64 * i];
    v[i] = t; s += t; s2 += t * t;
  }
  s = warp_sum(s); s2 = warp_sum(s2);
  float mean = s * (1.f / NC);
  float var = s2 * (1.f / NC) - mean * mean;
  float rs = rsqrtf(var + 1e-5f);
  int bb = row >> 11, t = row & 2047;
  unsigned short* yr = ypad + ((size_t)(bb * TPAD + t + 4)) * NC;
#pragma unroll
  for (int i = 0; i < 6; ++i) {
    int cc = lane + 64 * i;
    yr[cc] = f2bf((v[i] - mean) * rs * g[cc] + b[cc]);
  }
}

// zero the 4 guard rows top+bottom of each batch slab in ypad
__global__ __launch_bounds__(256) void k_zero_guard(unsigned short* __restrict__ ypad) {
  int i = blockIdx.x * 256 + threadIdx.x;   // 8*8*384 = 24576
  if (i >= 24576) return;
  int c = i % NC;
  int r = (i / NC) % 8;
  int b = i / (NC * 8);
  int t = (r < 4) ? r : (2048 + r);         // rows 0..3 and 2052..2055
  ypad[((size_t)b * TPAD + t) * NC + c] = 0;
}

// pack + convert cw[f][c][kk] -> cwp[f][kk*384+c] bf16. One block per f-row,
// coalesced load -> LDS -> coalesced store (LDS read stride 9: conflict-free).
__global__ __launch_bounds__(256) void k_pack_cw2(const float* __restrict__ cw,
    unsigned short* __restrict__ cwp) {
  __shared__ float s[NKI];
  int f = blockIdx.x;
  const float* src = cw + (size_t)f * NKI;
  for (int i = threadIdx.x; i < NKI; i += 256) s[i] = src[i];
  __syncthreads();
  unsigned short* dst = cwp + (size_t)f * NKI;
  for (int i = threadIdx.x; i < NKI; i += 256) {
    int kk = i / NC, cc = i - kk * NC;
    dst[i] = f2bf(s[cc * 9 + kk]);
  }
}

// fp32 -> bf16 with scale (scale folds q's 192^-0.5 into qw)
__global__ __launch_bounds__(256) void k_cvt_scale(const float* __restrict__ x,
    unsigned short* __restrict__ y, int n, float scale) {
  int i = blockIdx.x * 256 + threadIdx.x;
  if (i < n) y[i] = f2bf(x[i] * scale);
}

// Projection GEMM: A[M,K]bf16 @ W[N=384,K]bf16^T. 128x128 tile, m97 structure.
// mode 0: bf16 row write to Cb. mode 1: Cf += acc (fused residual, o-proj).
// mode 2: bf16 transposed write (v-proj -> vtb layout [(b*2+h)*192+d][512]).
__global__ __launch_bounds__(256) void k_pgemm_mfma(
    const unsigned short* __restrict__ A,
    const unsigned short* __restrict__ W,
    unsigned short* __restrict__ Cb,
    float* __restrict__ Cf,
    int K, int mode) {
  __shared__ unsigned short As[128 * 32];
  __shared__ unsigned short Bs[128 * 32];
  const int bn = blockIdx.x * 128;
  const int bm = blockIdx.y * 128;
  const int tid = threadIdx.x;
  const int lane = tid & 63, wv = tid >> 6;
  const int wr = (wv >> 1) * 64, wc = (wv & 1) * 64;
  f32x4 acc[4][4] = {};

  const int chunk = wv * 2;
  const int rloc = chunk * 16 + (lane >> 2);
  const int slot = (lane & 3) * 8;
  const size_t abase = ((size_t)(bm + rloc)) * K + slot;
  const size_t bbase = ((size_t)(bn + rloc)) * K + slot;
  unsigned short* AsW0 = &As[chunk * 512];
  unsigned short* AsW1 = &As[(chunk + 1) * 512];
  unsigned short* BsW0 = &Bs[chunk * 512];
  unsigned short* BsW1 = &Bs[(chunk + 1) * 512];

  const int rsel = lane & 15, ksel = (lane >> 4) * 8;

  for (int kt = 0; kt < K; kt += 32) {
    GLOAD16(A + abase + kt, AsW0);
    GLOAD16(A + abase + kt + (size_t)16 * K, AsW1);
    GLOAD16(W + bbase + kt, BsW0);
    GLOAD16(W + bbase + kt + (size_t)16 * K, BsW1);
    __syncthreads();
    bf16x8 af[4], bfr[4];
#pragma unroll
    for (int m = 0; m < 4; ++m)
      af[m] = *(const bf16x8*)&As[(wr + m * 16 + rsel) * 32 + ksel];
#pragma unroll
    for (int n = 0; n < 4; ++n)
      bfr[n] = *(const bf16x8*)&Bs[(wc + n * 16 + rsel) * 32 + ksel];
#pragma unroll
    for (int m = 0; m < 4; ++m)
#pragma unroll
      for (int n = 0; n < 4; ++n)
        acc[m][n] = __builtin_amdgcn_mfma_f32_16x16x32_bf16(af[m], bfr[n], acc[m][n], 0, 0, 0);
    __syncthreads();
  }

  const int col0 = bn + wc + (lane & 15);
  const int row0 = bm + wr + (lane >> 4) * 4;
#pragma unroll
  for (int m = 0; m < 4; ++m) {
#pragma unroll
    for (int n = 0; n < 4; ++n) {
      int col = col0 + n * 16;
#pragma unroll
      for (int r = 0; r < 4; ++r) {
        int row = row0 + m * 16 + r;
        if (mode == 0) {
          Cb[(size_t)row * NC + col] = f2bf(acc[m][n][r]);
        } else if (mode == 1) {
          size_t oi = (size_t)row * NC + col;
          Cf[oi] = acc[m][n][r] + Cf[oi];
        } else {
          // vtb[(b*384 + col)*512 + j], b = row>>9, j = row&511
          Cb[((size_t)((row >> 9) * 384 + col)) * 512 + (row & 511)] = f2bf(acc[m][n][r]);
        }
      }
    }
  }
}

// Conv1d(C->4C,k=9,SAME) implicit GEMM. 256x128 tile, BK=64, 8 waves (4Mx2N),
// double-buffered LDS, distance-2 prefetch with counted vmcnt (never 0 mid-loop),
// granule-XOR swizzle (pre-swizzled global src + XOR'd ds_read).
// Fused (+cb)*9^-0.5 -> gelu(exact) -> bf16 store.
__global__ __launch_bounds__(512) void k_conv_mfma(
    const unsigned short* __restrict__ Ypad,
    const unsigned short* __restrict__ Wp,
    const float* __restrict__ cb,
    unsigned short* __restrict__ H) {
  __shared__ unsigned short As[2][256 * 64];   // 64 KB
  __shared__ unsigned short Bs[2][128 * 64];   // 32 KB
  const int bm = blockIdx.x * 256;
  const int bn = blockIdx.y * 128;
  const int b = bm >> 11, t0 = bm & 2047;
  const int tid = threadIdx.x;
  const int lane = tid & 63, wv = tid >> 6;
  const int wvM = wv >> 1, wvN = wv & 1;
  const int rsel = lane & 15, ghi = lane >> 4;
  const int l8 = lane >> 3, g8 = lane & 7;
  const int gsrc = (g8 ^ l8) * 8;              // pre-swizzled source granule (shorts)

  f32x4 acc[4][4] = {};

  const size_t arow0 = (size_t)(b * TPAD + t0 + wv * 32 + l8);   // A stage row (lane)
  const size_t brow0 = (size_t)(bn + wv * 16 + l8);              // B stage row (lane)

#define CONV_STAGE(T, DB)                                                     \
  {                                                                           \
    const int kt_ = (T) * 64;                                                 \
    const int kk_ = kt_ / NC;                                                 \
    const int c0_ = kt_ - kk_ * NC;                                           \
    const size_t asrc_ = (arow0 + kk_) * NC + c0_ + gsrc;                     \
    GLOAD16(Ypad + asrc_, &As[DB][(wv * 32) * 64]);                           \
    GLOAD16(Ypad + asrc_ + (size_t)8 * NC, &As[DB][(wv * 32 + 8) * 64]);      \
    GLOAD16(Ypad + asrc_ + (size_t)16 * NC, &As[DB][(wv * 32 + 16) * 64]);    \
    GLOAD16(Ypad + asrc_ + (size_t)24 * NC, &As[DB][(wv * 32 + 24) * 64]);    \
    const size_t bsrc_ = brow0 * NKI + kt_ + gsrc;                            \
    GLOAD16(Wp + bsrc_, &Bs[DB][(wv * 16) * 64]);                             \
    GLOAD16(Wp + bsrc_ + (size_t)8 * NKI, &Bs[DB][(wv * 16 + 8) * 64]);       \
  }

  // prologue: stage tiles 0 and 1
  CONV_STAGE(0, 0);
  CONV_STAGE(1, 1);
  asm volatile("s_waitcnt vmcnt(6)" ::: "memory");
  __builtin_amdgcn_sched_barrier(0);
  __builtin_amdgcn_s_barrier();

  const int arow = wvM * 64;
  const int brow = wvN * 64;
  int db = 0;
  for (int t = 0; t < 54; ++t) {
    bf16x8 af[4][2], bfr[4][2];
#pragma unroll
    for (int m = 0; m < 4; ++m) {
      int r = arow + m * 16 + rsel;
#pragma unroll
      for (int k = 0; k < 2; ++k)
        af[m][k] = *(const bf16x8*)&As[db][r * 64 + (((k * 4 + ghi) ^ (r & 7)) * 8)];
    }
#pragma unroll
    for (int n = 0; n < 4; ++n) {
      int r = brow + n * 16 + rsel;
#pragma unroll
      for (int k = 0; k < 2; ++k)
        bfr[n][k] = *(const bf16x8*)&Bs[db][r * 64 + (((k * 4 + ghi) ^ (r & 7)) * 8)];
    }
    __builtin_amdgcn_s_setprio(1);
#pragma unroll
    for (int m = 0; m < 4; ++m)
#pragma unroll
      for (int n = 0; n < 4; ++n)
        acc[m][n] = __builtin_amdgcn_mfma_f32_16x16x32_bf16(af[m][0], bfr[n][0], acc[m][n], 0, 0, 0);
    __builtin_amdgcn_s_setprio(0);
    __builtin_amdgcn_sched_barrier(0);
    asm volatile("s_waitcnt lgkmcnt(0)" ::: "memory");   // all reads of tile t done
    __builtin_amdgcn_sched_barrier(0);
    __builtin_amdgcn_s_barrier();                        // ... in every wave
    if (t + 2 < 54) CONV_STAGE(t + 2, db);               // safe: buf[db] free now
    __builtin_amdgcn_s_setprio(1);
#pragma unroll
    for (int m = 0; m < 4; ++m)
#pragma unroll
      for (int n = 0; n < 4; ++n)
        acc[m][n] = __builtin_amdgcn_mfma_f32_16x16x32_bf16(af[m][1], bfr[n][1], acc[m][n], 0, 0, 0);
    __builtin_amdgcn_s_setprio(0);
    __builtin_amdgcn_sched_barrier(0);
    if (t + 2 < 54) {
      asm volatile("s_waitcnt vmcnt(6)" ::: "memory");   // tile t+1 landed; t+2 in flight
    } else {
      asm volatile("s_waitcnt vmcnt(0)" ::: "memory");   // epilogue drain
    }
    __builtin_amdgcn_sched_barrier(0);
    __builtin_amdgcn_s_barrier();
    db ^= 1;
  }
#undef CONV_STAGE

  const int col0 = bn + wvN * 64 + rsel;
  const int row0 = bm + wvM * 64 + ghi * 4;
#pragma unroll
  for (int m = 0; m < 4; ++m) {
#pragma unroll
    for (int n = 0; n < 4; ++n) {
      int col = col0 + n * 16;
      float cbv = cb[col];
#pragma unroll
      for (int r = 0; r < 4; ++r) {
        int row = row0 + m * 16 + r;
        float xv = (acc[m][n][r] + cbv) * 0.33333333333333333f;
        float ge = 0.5f * xv * (1.f + erff(xv * 0.70710678118654752f));
        H[(size_t)row * NF + col] = f2bf(ge);
      }
    }
  }
}

// FFN linear: x1a[m][n] += H[m][:]@lw[n][:] + lb[n].  bf16 MFMA, m97 structure.
__global__ __launch_bounds__(256) void k_lin_mfma(
    const unsigned short* __restrict__ H,
    const unsigned short* __restrict__ Wb,
    const float* __restrict__ lb,
    float* __restrict__ x1a) {
  __shared__ unsigned short As[128 * 32];
  __shared__ unsigned short Bs[128 * 32];
  const int bn = blockIdx.x * 128;
  const int bm = blockIdx.y * 128;
  const int tid = threadIdx.x;
  const int lane = tid & 63, wv = tid >> 6;
  const int wr = (wv >> 1) * 64, wc = (wv & 1) * 64;
  f32x4 acc[4][4] = {};

  const int chunk = wv * 2;
  const int rloc = chunk * 16 + (lane >> 2);
  const int slot = (lane & 3) * 8;
  const size_t abase = ((size_t)(bm + rloc)) * NF + slot;
  const size_t bbase = ((size_t)(bn + rloc)) * NF + slot;
  unsigned short* AsW0 = &As[chunk * 512];
  unsigned short* AsW1 = &As[(chunk + 1) * 512];
  unsigned short* BsW0 = &Bs[chunk * 512];
  unsigned short* BsW1 = &Bs[(chunk + 1) * 512];

  const int rsel = lane & 15, ksel = (lane >> 4) * 8;

  for (int kt = 0; kt < NF; kt += 32) {
    GLOAD16(H + abase + kt, AsW0);
    GLOAD16(H + abase + kt + (size_t)16 * NF, AsW1);
    GLOAD16(Wb + bbase + kt, BsW0);
    GLOAD16(Wb + bbase + kt + (size_t)16 * NF, BsW1);
    __syncthreads();
    bf16x8 af[4], bfr[4];
#pragma unroll
    for (int m = 0; m < 4; ++m)
      af[m] = *(const bf16x8*)&As[(wr + m * 16 + rsel) * 32 + ksel];
#pragma unroll
    for (int n = 0; n < 4; ++n)
      bfr[n] = *(const bf16x8*)&Bs[(wc + n * 16 + rsel) * 32 + ksel];
#pragma unroll
    for (int m = 0; m < 4; ++m)
#pragma unroll
      for (int n = 0; n < 4; ++n)
        acc[m][n] = __builtin_amdgcn_mfma_f32_16x16x32_bf16(af[m], bfr[n], acc[m][n], 0, 0, 0);
    __syncthreads();
  }

  const int col0 = bn + wc + (lane & 15);
  const int row0 = bm + wr + (lane >> 4) * 4;
#pragma unroll
  for (int m = 0; m < 4; ++m) {
#pragma unroll
    for (int n = 0; n < 4; ++n) {
      int col = col0 + n * 16;
      float lbv = lb[col];
#pragma unroll
      for (int r = 0; r < 4; ++r) {
        int row = row0 + m * 16 + r;
        size_t oi = (size_t)row * NC + col;
        x1a[oi] = acc[m][n][r] + lbv + x1a[oi];
      }
    }
  }
}

// Windowed cross-attention, MFMA flash-style. bf16 output (feeds o-projection).
__global__ __launch_bounds__(256) void k_attn_mfma(
    const unsigned short* __restrict__ qbb,   // [8*2048][384] bf16 (q*scaling folded in W)
    const unsigned short* __restrict__ kbb,   // [8*512][384] bf16
    const unsigned short* __restrict__ vtb,   // [(b*2+h)*192+d][512] bf16
    unsigned short* __restrict__ o, int guided, float* __restrict__ gl) {
  __shared__ unsigned short lds[32768];
  const int tid = threadIdx.x;
  const int lane = tid & 63, wv = tid >> 6;
  const int rsel = lane & 15, ghi = lane >> 4;
  const int idx = blockIdx.x;
  const int tg = idx & 31;
  const int bh = idx >> 5;
  const int h = bh & 1, b = bh >> 1;
  const int t0 = tg * 64;
  const int c0 = t0 >> 2;
  int klo = c0 - 51; if (klo < 0) klo = 0;
  klo &= ~7;                       // 16B-align for global_load_lds on vtb
  if (klo > 384) klo = 384;        // keep window inside [0,512)

  // Q fragments: A-operand layout, row = lane&15, k = ghi*8 (+32 per step)
  const unsigned short* qrow = qbb + (size_t)(b * NT1 + t0 + wv * 16 + rsel) * NC + h * ND;
  bf16x8 qf[6];
#pragma unroll
  for (int kk = 0; kk < 6; ++kk)
    qf[kk] = *(const bf16x8*)(qrow + kk * 32 + ghi * 8);

  // stage K window [128 keys][192] bf16, source pre-swizzled (granule ^ row&7)
  {
    const size_t kbase = (size_t)(b * NT2 + klo) * NC + h * ND;
#pragma unroll
    for (int it = 0; it < 12; ++it) {
      int g = it * 256 + tid;
      int row = g / 24, go = g % 24;
      int gs = go ^ (row & 7);
      GLOAD16(kbb + kbase + (size_t)row * NC + gs * 8, &lds[(it * 256 + wv * 64) * 8]);
    }
  }
  __syncthreads();

  // QK^T: 16 queries x 128 keys per wave
  f32x4 accs[8] = {};
#pragma unroll
  for (int kk = 0; kk < 6; ++kk) {
#pragma unroll
    for (int n = 0; n < 8; ++n) {
      int row = n * 16 + rsel;
      bf16x8 bfr = *(const bf16x8*)&lds[row * 192 + (((kk * 4 + ghi) ^ (rsel & 7)) * 8)];
      accs[n] = __builtin_amdgcn_mfma_f32_16x16x32_bf16(qf[kk], bfr, accs[n], 0, 0, 0);
    }
  }

  // masked softmax per query row; rows live on 16-lane groups (row=ghi*4+r, col=rsel)
  unsigned short* pl = &lds[24576 + wv * 2048];
  float gacc = 0.f;
  const int t0w = t0 + wv * 16;
#pragma unroll
  for (int r = 0; r < 4; ++r) {
    int t = t0w + ghi * 4 + r;
    int c = t >> 2;
    int loq = c - 51; if (loq < 0) loq = 0;
    int hiq = c + 51; if (hiq > NT2) hiq = NT2;
    float sv[8];
    float mx = -1e30f;
#pragma unroll
    for (int n = 0; n < 8; ++n) {
      int j = klo + n * 16 + rsel;
      float s = (j >= loq && j < hiq) ? accs[n][r] : -1e30f;
      sv[n] = s; mx = fmaxf(mx, s);
    }
#pragma unroll
    for (int off = 1; off < 16; off <<= 1) mx = fmaxf(mx, __shfl_xor(mx, off));
    float e[8]; float se = 0.f;
#pragma unroll
    for (int n = 0; n < 8; ++n) { e[n] = __expf(sv[n] - mx); se += e[n]; }
#pragma unroll
    for (int off = 1; off < 16; off <<= 1) se += __shfl_xor(se, off);
    float inv = 1.f / se;
    int q = ghi * 4 + r;
#pragma unroll
    for (int n = 0; n < 8; ++n) {
      float pv = e[n] * inv;
      int klocal = n * 16 + rsel;
      pl[q * 128 + (((klocal >> 3) ^ (q & 7)) * 8) + (klocal & 7)] = f2bf(pv);
      if (guided) {
        int j = klo + klocal;
        float d = (float)j * (1.f / NT2) - (float)t * (1.f / NT1);
        gacc += pv * (1.f - __expf(-(d * d) * 5.5555555556f));
      }
    }
  }
  if (guided) {
    gacc = warp_sum(gacc);
    if (lane == 0) atomicAdd(gl, gacc * (1.f / 16777216.f));
  }
  __syncthreads();

  // stage VT window [192 chans][128 keys] bf16 into the K buffer (reuse)
  {
    const size_t vbase = ((size_t)(b * 2 + h) * ND) * NT2 + klo;
#pragma unroll
    for (int it = 0; it < 12; ++it) {
      int g = it * 256 + tid;
      int row = g >> 4, go = g & 15;
      int gs = go ^ (row & 7);
      GLOAD16(vtb + vbase + (size_t)row * NT2 + gs * 8, &lds[(it * 256 + wv * 64) * 8]);
    }
  }
  __syncthreads();

  // PV: P[16x128] @ V[128x192] -> O[16x192]
  f32x4 acco[12] = {};
#pragma unroll
  for (int kt = 0; kt < 4; ++kt) {
    bf16x8 pa = *(const bf16x8*)&pl[rsel * 128 + (((kt * 4 + ghi) ^ (rsel & 7)) * 8)];
#pragma unroll
    for (int n = 0; n < 12; ++n) {
      int row = n * 16 + rsel;
      bf16x8 bfr = *(const bf16x8*)&lds[row * 128 + (((kt * 4 + ghi) ^ (rsel & 7)) * 8)];
      acco[n] = __builtin_amdgcn_mfma_f32_16x16x32_bf16(pa, bfr, acco[n], 0, 0, 0);
    }
  }

  unsigned short* obase = o + (size_t)(b * NT1 + t0w + ghi * 4) * NC + h * ND;
#pragma unroll
  for (int n = 0; n < 12; ++n) {
#pragma unroll
    for (int r = 0; r < 4; ++r) {
      obase[(size_t)r * NC + n * 16 + rsel] = f2bf(acco[n][r]);
    }
  }
}

extern "C" void kernel_launch(void* const* d_in, const int* in_sizes, int n_in,
                              void* d_out, int out_size, void* d_ws, size_t ws_size,
                              hipStream_t stream) {
  (void)in_sizes; (void)n_in; (void)out_size; (void)ws_size;
  const float* x1    = (const float*)d_in[0];
  const float* x2    = (const float*)d_in[1];
  const float* alpha = (const float*)d_in[2];
  const float* ln1_g = (const float*)d_in[3];
  const float* ln1_b = (const float*)d_in[4];
  const float* qw    = (const float*)d_in[5];
  const float* kw    = (const float*)d_in[6];
  const float* vw    = (const float*)d_in[7];
  const float* ow    = (const float*)d_in[8];
  const float* ln2_g = (const float*)d_in[9];
  const float* ln2_b = (const float*)d_in[10];
  const float* cw    = (const float*)d_in[11];
  const float* cb    = (const float*)d_in[12];
  const float* lw    = (const float*)d_in[13];
  const float* lb    = (const float*)d_in[14];
  const float* lnf_g = (const float*)d_in[15];
  const float* lnf_b = (const float*)d_in[16];
  float* out = (float*)d_out;
  float* gl = out + 6291456;   // guided-loss scalar slot

  float* p = (float*)d_ws;
  float* x1a = p; p += 6291456;    // x1 state [16384,384] f32
  // bf16 region (16B-aligned)
  unsigned short* us = (unsigned short*)p;
  unsigned short* x2b  = us; us += 1572864;            // x2+pos bf16 [4096][384]
  unsigned short* tmpb = us; us += 6291456;            // LN1 out / attn out bf16
  unsigned short* ypad = us; us += 8 * TPAD * NC;      // 6316032
  unsigned short* cwpb = us; us += 2 * (size_t)NF * NKI;   // 10616832 (both layers)
  unsigned short* lwb  = us; us += 2 * (size_t)NC * NF;    // 1179648 (both layers)
  unsigned short* hb   = us; us += (size_t)16384 * NF; // 25165824
  unsigned short* qbb  = us; us += 6291456;            // q bf16 [16384][384]
  unsigned short* kbb  = us; us += 1572864;            // k bf16 [4096][384]
  unsigned short* vtb  = us; us += 1572864;            // v^T bf16 [32*192][512]
  unsigned short* qwb  = us; us += 294912;             // weights bf16 (2 layers each)
  unsigned short* kwb  = us; us += 294912;
  unsigned short* vwb  = us; us += 294912;
  unsigned short* owb  = us; us += 294912;

  hipMemsetAsync(gl, 0, sizeof(float), stream);  // atomic accumulator, re-zeroed every launch
  k_zero_guard<<<96, 256, 0, stream>>>(ypad);
  k_add_pos2<<<12288, 256, 0, stream>>>(x1, alpha, x1a, NT1, 3145728);
  k_add_pos2_bf16<<<3072, 256, 0, stream>>>(x2, alpha, x2b, NT2, 786432);

  const float scaling = 0.07216878364870323f;   // 192^-0.5
  // weight conversions, both layers, hoisted
  k_cvt_scale<<<1152, 256, 0, stream>>>(qw, qwb, 294912, scaling);
  k_cvt_scale<<<1152, 256, 0, stream>>>(kw, kwb, 294912, 1.f);
  k_cvt_scale<<<1152, 256, 0, stream>>>(vw, vwb, 294912, 1.f);
  k_cvt_scale<<<1152, 256, 0, stream>>>(ow, owb, 294912, 1.f);
  k_cvt_scale<<<4608, 256, 0, stream>>>(lw, lwb, 1179648, 1.f);
  k_pack_cw2<<<3072, 256, 0, stream>>>(cw, cwpb);

  for (int l = 0; l < 2; ++l) {
    k_ln_bf16<<<4096, 256, 0, stream>>>(x1a, ln1_g + l * 384, ln1_b + l * 384, tmpb);
    k_pgemm_mfma<<<dim3(3, 128), 256, 0, stream>>>(tmpb, qwb + (size_t)l * 147456, qbb, nullptr, 384, 0);
    k_pgemm_mfma<<<dim3(3, 32), 256, 0, stream>>>(x2b, kwb + (size_t)l * 147456, kbb, nullptr, 384, 0);
    k_pgemm_mfma<<<dim3(3, 32), 256, 0, stream>>>(x2b, vwb + (size_t)l * 147456, vtb, nullptr, 384, 2);
    k_attn_mfma<<<512, 256, 0, stream>>>(qbb, kbb, vtb, tmpb, l == 0 ? 1 : 0, gl);
    k_pgemm_mfma<<<dim3(3, 128), 256, 0, stream>>>(tmpb, owb + (size_t)l * 147456, nullptr, x1a, 384, 1);
    // FFN: ln2 -> bf16 padded, conv implicit GEMM (deep-pipelined MFMA), linear (MFMA)
    k_ln_bf16p<<<4096, 256, 0, stream>>>(x1a, ln2_g + l * 384, ln2_b + l * 384, ypad);
    k_conv_mfma<<<dim3(64, 12), 512, 0, stream>>>(ypad, cwpb + (size_t)l * 5308416, cb + l * 1536, hb);
    k_lin_mfma<<<dim3(3, 128), 256, 0, stream>>>(hb, lwb + (size_t)l * 589824, lb + l * 384, x1a);
  }
  k_ln<<<4096, 256, 0, stream>>>(x1a, lnf_g, lnf_b, out, 16384);
}